// Round 14
// baseline (330.993 us; speedup 1.0000x reference)
//
#include <hip/hip_runtime.h>

#define EMBED 2048
#define HEAD 128
#define BATCH 8
#define SEQ 2048

typedef __attribute__((ext_vector_type(4))) float f32x4;
typedef __attribute__((ext_vector_type(8))) __bf16 bf16x8;
typedef __attribute__((ext_vector_type(8))) short short8;

static __device__ __forceinline__ ushort f2bf(float x){
    unsigned u = __float_as_uint(x);
    u += 0x7fffu + ((u >> 16) & 1u);
    return (ushort)(u >> 16);
}

#define MFMA16(a,b,c) __builtin_amdgcn_mfma_f32_16x16x32_bf16((a),(b),(c),0,0,0)

#define GLL16(g, l) __builtin_amdgcn_global_load_lds( \
    (const __attribute__((address_space(1))) void*)(g), \
    (__attribute__((address_space(3))) void*)(l), 16, 0, 0)

// ---------------- prep: W [2048][128] f32 -> W^T [3*128][2048] bf16 (LDS transpose) ----------------
__global__ __launch_bounds__(256) void prep_wt(const float* __restrict__ Wq,
                                               const float* __restrict__ Wk,
                                               const float* __restrict__ Wv,
                                               ushort* __restrict__ wt){
    __shared__ float ld[64][129];
    const int w  = blockIdx.y;
    const int k0 = blockIdx.x * 64;
    const int tid = threadIdx.x;
    const float* W = (w == 0) ? Wq : ((w == 1) ? Wk : Wv);
    #pragma unroll
    for (int ii = 0; ii < 32; ii++){
        int idx = tid + 256 * ii;
        int row = idx >> 7, col = idx & 127;
        ld[row][col] = W[(size_t)(k0 + row) * HEAD + col];
    }
    __syncthreads();
    int n  = tid >> 1;
    int kh = (tid & 1) * 32;
    __attribute__((aligned(16))) ushort tmp[32];
    #pragma unroll
    for (int ii = 0; ii < 32; ii++) tmp[ii] = f2bf(ld[kh + ii][n]);
    ushort* dst = wt + (size_t)(w * HEAD + n) * EMBED + k0 + kh;
    #pragma unroll
    for (int q = 0; q < 4; q++)
        *(short8*)(dst + q * 8) = *(const short8*)(tmp + q * 8);
}

// ---------------- Fused QKV GEMM (r13 production, unchanged) ----------------
__global__ __launch_bounds__(256, 2) void qkv_gemm(const float* __restrict__ x,
                                                   const ushort* __restrict__ wt,
                                                   const float* __restrict__ bq,
                                                   const float* __restrict__ bk,
                                                   const float* __restrict__ bv,
                                                   ushort* __restrict__ Qb,
                                                   ushort* __restrict__ Kb,
                                                   ushort* __restrict__ Vt){
    __shared__ char smem[81920];
    float* ts = (float*)smem;

    const int half  = blockIdx.x;
    const int mtile = blockIdx.y;
    const int tid   = threadIdx.x;
    const int lane  = tid & 63;
    const int wid   = tid >> 6;
    const int l15   = lane & 15, lhi = lane >> 4;
    const int xrow0 = mtile * 64;

    const ushort* wsrc_base = wt + (size_t)(half * 192) * EMBED;
    const int grow  = lane >> 3;
    const int gch   = lane & 7;
    const int xgrow = lane >> 4;
    const int xgch  = lane & 15;

    f32x4 acc[4][3];
    #pragma unroll
    for (int i = 0; i < 4; i++)
        #pragma unroll
        for (int j = 0; j < 3; j++) acc[i][j] = (f32x4){0.f,0.f,0.f,0.f};

    const int NK = EMBED / 64;

    {
        #pragma unroll
        for (int g = 0; g < 4; g++){
            int r0  = wid * 16 + g * 4;
            int row = r0 + xgrow;
            int cs  = xgch ^ (((row & 7) << 1) | ((row & 8) >> 3));
            GLL16(x + (size_t)(xrow0 + row) * EMBED + cs * 4, smem + r0 * 256);
        }
        #pragma unroll
        for (int g = 0; g < 6; g++){
            int r0  = wid * 48 + g * 8;
            int row = r0 + grow;
            GLL16(wsrc_base + (size_t)row * EMBED + ((gch ^ (row & 7)) * 8), smem + 32768 + r0 * 128);
        }
    }

    for (int kt = 0; kt < NK; ++kt){
        char* xs_c = smem + (kt & 1) * 16384;
        char* wl_c = smem + 32768 + (kt & 1) * 24576;
        char* xs_n = smem + ((kt + 1) & 1) * 16384;
        char* wl_n = smem + 32768 + ((kt + 1) & 1) * 24576;

        if (kt < NK - 1){
            const float* xsrc = x + (kt + 1) * 64;
            #pragma unroll
            for (int g = 0; g < 4; g++){
                int r0  = wid * 16 + g * 4;
                int row = r0 + xgrow;
                int cs  = xgch ^ (((row & 7) << 1) | ((row & 8) >> 3));
                GLL16(xsrc + (size_t)(xrow0 + row) * EMBED + cs * 4, xs_n + r0 * 256);
            }
            const ushort* wsrc = wsrc_base + (kt + 1) * 64;
            #pragma unroll
            for (int g = 0; g < 6; g++){
                int r0  = wid * 48 + g * 8;
                int row = r0 + grow;
                GLL16(wsrc + (size_t)row * EMBED + ((gch ^ (row & 7)) * 8), wl_n + r0 * 128);
            }
            asm volatile("s_waitcnt vmcnt(10)" ::: "memory");
        } else {
            asm volatile("s_waitcnt vmcnt(0)" ::: "memory");
        }
        __builtin_amdgcn_s_barrier();

        #pragma unroll
        for (int kc = 0; kc < 2; kc++){
            bf16x8 af[4], bfj[3];
            #pragma unroll
            for (int i = 0; i < 4; i++){
                int row = i * 16 + l15;
                int swz = ((row & 7) << 1) | ((row & 8) >> 3);
                int c0  = kc * 8 + lhi * 2;
                f32x4 lo = *(const f32x4*)(xs_c + row * 256 + ((c0    ) ^ swz) * 16);
                f32x4 hi = *(const f32x4*)(xs_c + row * 256 + ((c0 + 1) ^ swz) * 16);
                bf16x8 a;
                a[0] = (__bf16)lo[0]; a[1] = (__bf16)lo[1]; a[2] = (__bf16)lo[2]; a[3] = (__bf16)lo[3];
                a[4] = (__bf16)hi[0]; a[5] = (__bf16)hi[1]; a[6] = (__bf16)hi[2]; a[7] = (__bf16)hi[3];
                af[i] = a;
            }
            #pragma unroll
            for (int j = 0; j < 3; j++){
                int row = wid * 48 + j * 16 + l15;
                bfj[j] = *(const bf16x8*)(wl_c + row * 128 + (((kc*4 + lhi) ^ (l15 & 7)) * 16));
            }
            #pragma unroll
            for (int i = 0; i < 4; i++)
                #pragma unroll
                for (int j = 0; j < 3; j++)
                    acc[i][j] = MFMA16(af[i], bfj[j], acc[i][j]);
        }
        __builtin_amdgcn_s_barrier();
    }

    float bval[3];
    #pragma unroll
    for (int j = 0; j < 3; j++){
        int c = half * 192 + wid * 48 + j * 16 + l15;
        bval[j] = (c < 128) ? bq[c] : ((c < 256) ? bk[c - 128] : bv[c - 256]);
    }
    #pragma unroll
    for (int j = 0; j < 3; j++){
        int cb = half * 192 + wid * 48 + j * 16;
        if (cb < 256){
            ushort* dst = (cb < 128) ? Qb : Kb;
            int cl = (cb < 128) ? (cb + l15) : (cb - 128 + l15);
            #pragma unroll
            for (int i = 0; i < 4; i++)
                #pragma unroll
                for (int r = 0; r < 4; r++)
                    dst[(size_t)(mtile*64 + i*16 + lhi*4 + r) * HEAD + cl] = f2bf(acc[i][j][r] + bval[j]);
        }
    }
    if (half == 1){
        __syncthreads();
        #pragma unroll
        for (int j = 0; j < 3; j++){
            int cb = 192 + wid * 48 + j * 16;
            if (cb >= 256){
                int vc = cb - 256 + l15;
                #pragma unroll
                for (int i = 0; i < 4; i++)
                    #pragma unroll
                    for (int r = 0; r < 4; r++)
                        ts[(i*16 + lhi*4 + r) * 132 + vc] = acc[i][j][r] + bval[j];
            }
        }
        __syncthreads();
        int n  = tid >> 1;
        int mc = (tid & 1) * 32;
        int bb = mtile >> 5;
        int trow = (mtile & 31) * 64 + mc;
        __attribute__((aligned(16))) ushort tmp[32];
        #pragma unroll
        for (int ii = 0; ii < 32; ii++) tmp[ii] = f2bf(ts[(mc + ii) * 132 + n]);
        ushort* dst = Vt + ((size_t)(bb * HEAD + n)) * SEQ + trow;
        #pragma unroll
        for (int q = 0; q < 4; q++)
            *(short8*)(dst + q * 8) = *(const short8*)(tmp + q * 8);
    }
}

// ---------------- DIAG A: staging + vmcnt + barriers only (REP=2) ----------------
__global__ __launch_bounds__(256, 2) void diag_stage(const float* __restrict__ x,
                                                     const ushort* __restrict__ wt,
                                                     float* __restrict__ outd){
    __shared__ char smem[81920];
    const int half  = blockIdx.x;
    const int mtile = blockIdx.y;
    const int tid   = threadIdx.x;
    const int lane  = tid & 63;
    const int wid   = tid >> 6;
    const int xrow0 = mtile * 64;
    const ushort* wsrc_base = wt + (size_t)(half * 192) * EMBED;
    const int grow  = lane >> 3;
    const int gch   = lane & 7;
    const int xgrow = lane >> 4;
    const int xgch  = lane & 15;
    const int NK = EMBED / 64;

    for (int rep = 0; rep < 2; rep++){
        #pragma unroll
        for (int g = 0; g < 4; g++){
            int r0  = wid * 16 + g * 4;
            int row = r0 + xgrow;
            int cs  = xgch ^ (((row & 7) << 1) | ((row & 8) >> 3));
            GLL16(x + (size_t)(xrow0 + row) * EMBED + cs * 4, smem + r0 * 256);
        }
        #pragma unroll
        for (int g = 0; g < 6; g++){
            int r0  = wid * 48 + g * 8;
            int row = r0 + grow;
            GLL16(wsrc_base + (size_t)row * EMBED + ((gch ^ (row & 7)) * 8), smem + 32768 + r0 * 128);
        }
        for (int kt = 0; kt < NK; ++kt){
            char* xs_n = smem + ((kt + 1) & 1) * 16384;
            char* wl_n = smem + 32768 + ((kt + 1) & 1) * 24576;
            if (kt < NK - 1){
                const float* xsrc = x + (kt + 1) * 64;
                #pragma unroll
                for (int g = 0; g < 4; g++){
                    int r0  = wid * 16 + g * 4;
                    int row = r0 + xgrow;
                    int cs  = xgch ^ (((row & 7) << 1) | ((row & 8) >> 3));
                    GLL16(xsrc + (size_t)(xrow0 + row) * EMBED + cs * 4, xs_n + r0 * 256);
                }
                const ushort* wsrc = wsrc_base + (kt + 1) * 64;
                #pragma unroll
                for (int g = 0; g < 6; g++){
                    int r0  = wid * 48 + g * 8;
                    int row = r0 + grow;
                    GLL16(wsrc + (size_t)row * EMBED + ((gch ^ (row & 7)) * 8), wl_n + r0 * 128);
                }
                asm volatile("s_waitcnt vmcnt(10)" ::: "memory");
            } else {
                asm volatile("s_waitcnt vmcnt(0)" ::: "memory");
            }
            __builtin_amdgcn_s_barrier();
            __builtin_amdgcn_s_barrier();
        }
    }
    outd[((size_t)mtile * 2 + half) * 256 + tid] = *(const float*)(smem + tid * 4);
}

// ---------------- DIAG B: LDS reads + cvt + MFMA + barriers only (REP=2) ----------------
__global__ __launch_bounds__(256, 2) void diag_compute(float* __restrict__ outd){
    __shared__ char smem[81920];
    const int tid  = threadIdx.x;
    const int lane = tid & 63;
    const int wid  = tid >> 6;
    const int l15  = lane & 15, lhi = lane >> 4;
    const int NK = EMBED / 64;

    for (int i = tid; i < 81920/4; i += 256) ((float*)smem)[i] = 1.0f;
    __syncthreads();

    f32x4 acc[4][3];
    #pragma unroll
    for (int i = 0; i < 4; i++)
        #pragma unroll
        for (int j = 0; j < 3; j++) acc[i][j] = (f32x4){0.f,0.f,0.f,0.f};

    for (int rep = 0; rep < 2; rep++){
        for (int kt = 0; kt < NK; ++kt){
            char* xs_c = smem + (kt & 1) * 16384;
            char* wl_c = smem + 32768 + (kt & 1) * 24576;
            __builtin_amdgcn_s_barrier();
            #pragma unroll
            for (int kc = 0; kc < 2; kc++){
                bf16x8 af[4], bfj[3];
                #pragma unroll
                for (int i = 0; i < 4; i++){
                    int row = i * 16 + l15;
                    int swz = ((row & 7) << 1) | ((row & 8) >> 3);
                    int c0  = kc * 8 + lhi * 2;
                    f32x4 lo = *(const f32x4*)(xs_c + row * 256 + ((c0    ) ^ swz) * 16);
                    f32x4 hi = *(const f32x4*)(xs_c + row * 256 + ((c0 + 1) ^ swz) * 16);
                    bf16x8 a;
                    a[0] = (__bf16)lo[0]; a[1] = (__bf16)lo[1]; a[2] = (__bf16)lo[2]; a[3] = (__bf16)lo[3];
                    a[4] = (__bf16)hi[0]; a[5] = (__bf16)hi[1]; a[6] = (__bf16)hi[2]; a[7] = (__bf16)hi[3];
                    af[i] = a;
                }
                #pragma unroll
                for (int j = 0; j < 3; j++){
                    int row = wid * 48 + j * 16 + l15;
                    bfj[j] = *(const bf16x8*)(wl_c + row * 128 + (((kc*4 + lhi) ^ (l15 & 7)) * 16));
                }
                #pragma unroll
                for (int i = 0; i < 4; i++)
                    #pragma unroll
                    for (int j = 0; j < 3; j++)
                        acc[i][j] = MFMA16(af[i], bfj[j], acc[i][j]);
            }
            __builtin_amdgcn_s_barrier();
        }
    }
    float s = 0.f;
    #pragma unroll
    for (int i = 0; i < 4; i++)
        #pragma unroll
        for (int j = 0; j < 3; j++)
            s += acc[i][j][0] + acc[i][j][1] + acc[i][j][2] + acc[i][j][3];
    outd[((size_t)blockIdx.y * 2 + blockIdx.x) * 256 + tid] = s;
}

// ---------------- DIAG C: MFMA + barriers only, register-fed (REP=4) ----------------
__global__ __launch_bounds__(256, 2) void diag_mfma(float* __restrict__ outd){
    __shared__ char smem[81920];
    const int tid = threadIdx.x;
    if (tid == 0) smem[0] = 1;   // keep LDS allocated for occupancy parity
    __syncthreads();
    const int NK = EMBED / 64;

    bf16x8 af[4], bfj[3];
    #pragma unroll
    for (int i = 0; i < 4; i++)
        #pragma unroll
        for (int e = 0; e < 8; e++) af[i][e] = (__bf16)(float)((tid + i + e) & 7);
    #pragma unroll
    for (int j = 0; j < 3; j++)
        #pragma unroll
        for (int e = 0; e < 8; e++) bfj[j][e] = (__bf16)(float)((tid + j * 3 + e) & 7);

    f32x4 acc[4][3];
    #pragma unroll
    for (int i = 0; i < 4; i++)
        #pragma unroll
        for (int j = 0; j < 3; j++) acc[i][j] = (f32x4){0.f,0.f,0.f,0.f};

    for (int rep = 0; rep < 4; rep++){
        for (int kt = 0; kt < NK; ++kt){
            __builtin_amdgcn_s_barrier();
            #pragma unroll
            for (int kc = 0; kc < 2; kc++)
                #pragma unroll
                for (int i = 0; i < 4; i++)
                    #pragma unroll
                    for (int j = 0; j < 3; j++)
                        acc[i][j] = MFMA16(af[i], bfj[j], acc[i][j]);
            __builtin_amdgcn_s_barrier();
        }
    }
    float s = 0.f;
    #pragma unroll
    for (int i = 0; i < 4; i++)
        #pragma unroll
        for (int j = 0; j < 3; j++)
            s += acc[i][j][0] + acc[i][j][1] + acc[i][j][2] + acc[i][j][3];
    outd[((size_t)blockIdx.y * 2 + blockIdx.x) * 256 + tid] = s + (float)smem[0];
}

// ---------------- Flash attention, causal, kv-split x2, async-staged ----------------
__global__ __launch_bounds__(256) void attn(const ushort* __restrict__ Qb,
                                            const ushort* __restrict__ Kb,
                                            const ushort* __restrict__ Vt,
                                            float* __restrict__ po,
                                            float* __restrict__ pm,
                                            float* __restrict__ pl){
    __shared__ char smem[40960];
    char* Ks = smem;
    char* Vs = smem + 16384;
    char* Ps = smem + 32768;

    const int slot = blockIdx.x;
    const int b    = blockIdx.y;
    const int qi   = slot >> 1;
    const int qt   = (b < 4) ? qi : (31 - qi);
    const int half = slot & 1;
    const int NT   = qt + 1;
    const int tmid = (NT + 1) >> 1;
    const int t0   = half ? tmid : 0;
    const int t1   = half ? NT : tmid;

    const int qb    = qt * 64;
    const int tid   = threadIdx.x;
    const int lane  = tid & 63, wid = tid >> 6;
    const int l15   = lane & 15, lhi = lane >> 4;
    const float scale = 0.08838834764831845f;

    bf16x8 qf[4];
    {
        const ushort* qp = Qb + ((size_t)(b * SEQ + qb + wid * 16 + l15)) * HEAD;
        #pragma unroll
        for (int kc = 0; kc < 4; kc++)
            qf[kc] = *(const bf16x8*)(qp + kc * 32 + lhi * 8);
    }

    f32x4 o[8];
    #pragma unroll
    for (int d = 0; d < 8; d++) o[d] = (f32x4){0.f,0.f,0.f,0.f};
    float mr[4] = {-1e30f,-1e30f,-1e30f,-1e30f};
    float lr[4] = {0.f,0.f,0.f,0.f};

    char* Pw = Ps + wid * 2048;

    const int krow = tid >> 4, kch = tid & 15;
    const int vd   = tid >> 3, vch = tid & 7;

    short8 kr[4], vr[4];
    {
        const int kvb = t0 * 64;
        #pragma unroll
        for (int j = 0; j < 4; j++)
            kr[j] = *(const short8*)(Kb + ((size_t)(b * SEQ + kvb + krow + 16*j)) * HEAD + kch * 8);
        #pragma unroll
        for (int j = 0; j < 4; j++)
            vr[j] = *(const short8*)(Vt + ((size_t)(b * HEAD + vd + 32*j)) * SEQ + kvb + vch * 8);
    }

    for (int t = t0; t < t1; ++t){
        __syncthreads();
        #pragma unroll
        for (int j = 0; j < 4; j++){
            int row = krow + 16*j;
            *(short8*)(Ks + row * 256 + ((kch ^ (row & 15)) * 16)) = kr[j];
        }
        #pragma unroll
        for (int j = 0; j < 4; j++){
            int d = vd + 32*j;
            *(short8*)(Vs + d * 128 + ((vch ^ (d & 7)) * 16)) = vr[j];
        }
        if (t + 1 < t1){
            const int kvb2 = (t + 1) * 64;
            #pragma unroll
            for (int j = 0; j < 4; j++)
                kr[j] = *(const short8*)(Kb + ((size_t)(b * SEQ + kvb2 + krow + 16*j)) * HEAD + kch * 8);
            #pragma unroll
            for (int j = 0; j < 4; j++)
                vr[j] = *(const short8*)(Vt + ((size_t)(b * HEAD + vd + 32*j)) * SEQ + kvb2 + vch * 8);
        }
        asm volatile("s_waitcnt lgkmcnt(0)" ::: "memory");
        __builtin_amdgcn_s_barrier();
        __builtin_amdgcn_sched_barrier(0);

        const int kvb = t * 64;
        f32x4 s[4];
        #pragma unroll
        for (int ns = 0; ns < 4; ns++){
            s[ns] = (f32x4){0.f,0.f,0.f,0.f};
            int row = ns * 16 + l15;
            #pragma unroll
            for (int kc = 0; kc < 4; kc++){
                int ch = (kc * 4 + lhi) ^ (row & 15);
                bf16x8 bfr = *(const bf16x8*)(Ks + row * 256 + ch * 16);
                s[ns] = MFMA16(qf[kc], bfr, s[ns]);
            }
        }

        float mx[4];
        #pragma unroll
        for (int r = 0; r < 4; r++){
            #pragma unroll
            for (int ns = 0; ns < 4; ns++){
                float v = s[ns][r] * scale;
                if (t == qt){
                    int kvg = kvb + ns * 16 + l15;
                    int qg  = qb + wid * 16 + lhi * 4 + r;
                    if (kvg > qg) v = -1e30f;
                }
                s[ns][r] = v;
            }
            float m0 = fmaxf(fmaxf(s[0][r], s[1][r]), fmaxf(s[2][r], s[3][r]));
            m0 = fmaxf(m0, __shfl_xor(m0, 1));
            m0 = fmaxf(m0, __shfl_xor(m0, 2));
            m0 = fmaxf(m0, __shfl_xor(m0, 4));
            m0 = fmaxf(m0, __shfl_xor(m0, 8));
            mx[r] = m0;
        }
        float alpha[4];
        #pragma unroll
        for (int r = 0; r < 4; r++){
            float mn = fmaxf(mr[r], mx[r]);
            alpha[r] = __expf(mr[r] - mn);
            mr[r] = mn;
            float sum = 0.f;
            #pragma unroll
            for (int ns = 0; ns < 4; ns++){
                float p = __expf(s[ns][r] - mn);
                s[ns][r] = p;
                sum += p;
            }
            sum += __shfl_xor(sum, 1);
            sum += __shfl_xor(sum, 2);
            sum += __shfl_xor(sum, 4);
            sum += __shfl_xor(sum, 8);
            lr[r] = lr[r] * alpha[r] + sum;
        }
        #pragma unroll
        for (int d = 0; d < 8; d++)
            #pragma unroll
            for (int r = 0; r < 4; r++) o[d][r] *= alpha[r];

        #pragma unroll
        for (int ns = 0; ns < 4; ns++)
            #pragma unroll
            for (int r = 0; r < 4; r++){
                int row = lhi * 4 + r;
                int byteoff = row * 128 + (((ns * 16 + l15) * 2) ^ ((row & 7) << 4));
                *(ushort*)(Pw + byteoff) = f2bf(s[ns][r]);
            }
        asm volatile("s_waitcnt lgkmcnt(0)" ::: "memory");
        __builtin_amdgcn_sched_barrier(0);

        #pragma unroll
        for (int kc = 0; kc < 2; kc++){
            int abyte = l15 * 128 + ((kc * 64 + lhi * 16) ^ ((l15 & 7) << 4));
            bf16x8 af = *(const bf16x8*)(Pw + abyte);
            #pragma unroll
            for (int ds = 0; ds < 8; ds++){
                int drow = ds * 16 + l15;
                int bbyte = drow * 128 + ((kc * 64 + lhi * 16) ^ ((drow & 7) << 4));
                bf16x8 bfr = *(const bf16x8*)(Vs + bbyte);
                o[ds] = MFMA16(af, bfr, o[ds]);
            }
        }
    }

    float* pob = po + ((size_t)half * 16384 + (size_t)b * SEQ) * HEAD;
    #pragma unroll
    for (int r = 0; r < 4; r++){
        int q = qb + wid * 16 + lhi * 4 + r;
        #pragma unroll
        for (int ds = 0; ds < 8; ds++)
            pob[(size_t)q * HEAD + ds * 16 + l15] = o[ds][r];
        if (l15 == 0){
            pm[half * 16384 + b * SEQ + q] = mr[r];
            pl[half * 16384 + b * SEQ + q] = lr[r];
        }
    }
}

// ---------------- merge two kv-halves ----------------
__global__ __launch_bounds__(256) void merge(const float* __restrict__ po,
                                             const float* __restrict__ pm,
                                             const float* __restrict__ pl,
                                             float* __restrict__ out){
    int g = blockIdx.x * 256 + threadIdx.x;
    int row = g >> 2;
    int dq  = (g & 3) * 32;
    float m0 = pm[row], m1 = pm[16384 + row];
    float l0 = pl[row], l1 = pl[16384 + row];
    float M  = fmaxf(m0, m1);
    float w0 = __expf(m0 - M), w1 = __expf(m1 - M);
    float inv = 1.0f / (w0 * l0 + w1 * l1);
    const float4* p0 = (const float4*)(po + (size_t)row * HEAD + dq);
    const float4* p1 = (const float4*)(po + (size_t)(16384 + row) * HEAD + dq);
    float4* op = (float4*)(out + (size_t)row * HEAD + dq);
    #pragma unroll
    for (int i = 0; i < 8; i++){
        float4 a = p0[i], c = p1[i];
        float4 r;
        r.x = (w0*a.x + w1*c.x) * inv;
        r.y = (w0*a.y + w1*c.y) * inv;
        r.z = (w0*a.z + w1*c.z) * inv;
        r.w = (w0*a.w + w1*c.w) * inv;
        op[i] = r;
    }
}

extern "C" void kernel_launch(void* const* d_in, const int* in_sizes, int n_in,
                              void* d_out, int out_size, void* d_ws, size_t ws_size,
                              hipStream_t stream){
    const float* x  = (const float*)d_in[0];
    const float* Wq = (const float*)d_in[1];
    const float* bq = (const float*)d_in[2];
    const float* Wk = (const float*)d_in[3];
    const float* bk = (const float*)d_in[4];
    const float* Wv = (const float*)d_in[5];
    const float* bv = (const float*)d_in[6];
    float* out = (float*)d_out;

    char* ws = (char*)d_ws;
    ushort* Qb = (ushort*)ws;
    ushort* Kb = (ushort*)(ws + (size_t)4  * 1024 * 1024);
    ushort* Vt = (ushort*)(ws + (size_t)8  * 1024 * 1024);
    ushort* Wt = (ushort*)(ws + (size_t)12 * 1024 * 1024);
    float*  po = (float*) (ws + (size_t)14 * 1024 * 1024);   // diag scratch lives here; attn overwrites
    float*  pm = (float*) (ws + (size_t)31 * 1024 * 1024);
    float*  pl = (float*) (ws + (size_t)31 * 1024 * 1024 + 262144);
    float* dgA = (float*) (ws + (size_t)14 * 1024 * 1024);
    float* dgB = (float*) (ws + (size_t)15 * 1024 * 1024);
    float* dgC = (float*) (ws + (size_t)16 * 1024 * 1024);

    prep_wt    <<<dim3(32, 3), 256, 0, stream>>>(Wq, Wk, Wv, Wt);
    qkv_gemm   <<<dim3(2, 256), 256, 0, stream>>>(x, Wt, bq, bk, bv, Qb, Kb, Vt);
    diag_stage <<<dim3(2, 256), 256, 0, stream>>>(x, Wt, dgA);
    diag_compute<<<dim3(2, 256), 256, 0, stream>>>(dgB);
    diag_mfma  <<<dim3(2, 256), 256, 0, stream>>>(dgC);
    attn       <<<dim3(64, 8), 256, 0, stream>>>(Qb, Kb, Vt, po, pm, pl);
    merge      <<<256, 256, 0, stream>>>(po, pm, pl, out);
}

// Round 15
// 122.870 us; speedup vs baseline: 2.6938x; 2.6938x over previous
//
#include <hip/hip_runtime.h>

#define EMBED 2048
#define HEAD 128
#define BATCH 8
#define SEQ 2048

typedef __attribute__((ext_vector_type(4))) float f32x4;
typedef __attribute__((ext_vector_type(8))) __bf16 bf16x8;
typedef __attribute__((ext_vector_type(8))) short short8;

static __device__ __forceinline__ ushort f2bf(float x){
    unsigned u = __float_as_uint(x);
    u += 0x7fffu + ((u >> 16) & 1u);
    return (ushort)(u >> 16);
}

#define MFMA16(a,b,c) __builtin_amdgcn_mfma_f32_16x16x32_bf16((a),(b),(c),0,0,0)

#define GLL16(g, l) __builtin_amdgcn_global_load_lds( \
    (const __attribute__((address_space(1))) void*)(g), \
    (__attribute__((address_space(3))) void*)(l), 16, 0, 0)

// ---------------- prep: W [2048][128] f32 -> W^T [3*128][2048] bf16 (LDS transpose) ----------------
__global__ __launch_bounds__(256) void prep_wt(const float* __restrict__ Wq,
                                               const float* __restrict__ Wk,
                                               const float* __restrict__ Wv,
                                               ushort* __restrict__ wt){
    __shared__ float ld[64][129];
    const int w  = blockIdx.y;
    const int k0 = blockIdx.x * 64;
    const int tid = threadIdx.x;
    const float* W = (w == 0) ? Wq : ((w == 1) ? Wk : Wv);
    #pragma unroll
    for (int ii = 0; ii < 32; ii++){
        int idx = tid + 256 * ii;
        int row = idx >> 7, col = idx & 127;
        ld[row][col] = W[(size_t)(k0 + row) * HEAD + col];
    }
    __syncthreads();
    int n  = tid >> 1;
    int kh = (tid & 1) * 32;
    __attribute__((aligned(16))) ushort tmp[32];
    #pragma unroll
    for (int ii = 0; ii < 32; ii++) tmp[ii] = f2bf(ld[kh + ii][n]);
    ushort* dst = wt + (size_t)(w * HEAD + n) * EMBED + k0 + kh;
    #pragma unroll
    for (int q = 0; q < 4; q++)
        *(short8*)(dst + q * 8) = *(const short8*)(tmp + q * 8);
}

// ---------------- Fused QKV GEMM: DEPTH-2 pipelined pure-GLL staging ----------------
// BM=64, BN=192 (n-split x2), BK=32, NK=64. 256 thr / 4 waves (pure n-split; wave 64m x 48n).
// Grid (2,256)=512 = 2 blocks/CU. LDS 60KB: x f32 [64][128B] x3 + W bf16 [192][64B] x3 (triple buffer).
// Loop: issue tile kt+2 (5 GLL/thread) | vmcnt(10) = 2 tiles stay in flight | barrier | 12 MFMA | barrier.
__global__ __launch_bounds__(256, 2) void qkv_gemm(const float* __restrict__ x,
                                                   const ushort* __restrict__ wt,
                                                   const float* __restrict__ bq,
                                                   const float* __restrict__ bk,
                                                   const float* __restrict__ bv,
                                                   ushort* __restrict__ Qb,
                                                   ushort* __restrict__ Kb,
                                                   ushort* __restrict__ Vt){
    __shared__ char smem[61440];
    // xs(b) = smem + b*8192           [64][128B] f32, chunk-swizzled (^row&7)
    // wl(b) = smem + 24576 + b*12288  [192][64B] bf16, chunk-swizzled (^row&3)
    float* ts = (float*)smem;          // epilogue V transpose overlay [64][132] f32

    const int half  = blockIdx.x;
    const int mtile = blockIdx.y;
    const int tid   = threadIdx.x;
    const int lane  = tid & 63;
    const int wid   = tid >> 6;        // 0..3 pure n-split
    const int l15   = lane & 15, lhi = lane >> 4;
    const int xrow0 = mtile * 64;

    const ushort* wsrc_base = wt + (size_t)(half * 192) * EMBED;
    const int NK = EMBED / 32;         // 64

    f32x4 acc[4][3];
    #pragma unroll
    for (int i = 0; i < 4; i++)
        #pragma unroll
        for (int j = 0; j < 3; j++) acc[i][j] = (f32x4){0.f,0.f,0.f,0.f};

    // stage(tile kt -> buffer b): x 2 chunks + W 3 chunks per thread
    #define STAGE(KT, B) do{                                                           \
        const float*  xsrc = x + (size_t)xrow0 * EMBED + (KT) * 32;                    \
        const ushort* wsrc = wsrc_base + (KT) * 32;                                    \
        char* xb = smem + (B) * 8192;                                                  \
        char* wb = smem + 24576 + (B) * 12288;                                         \
        _Pragma("unroll")                                                              \
        for (int g = 0; g < 2; g++){                                                   \
            int c   = tid + 256 * g;                                                   \
            int row = c >> 3, ch = c & 7;                                              \
            int cs  = ch ^ (row & 7);                                                  \
            GLL16(xsrc + (size_t)row * EMBED + cs * 4, xb + c * 16);                   \
        }                                                                              \
        _Pragma("unroll")                                                              \
        for (int g = 0; g < 3; g++){                                                   \
            int c   = tid + 256 * g;                                                   \
            int row = c >> 2, ch = c & 3;                                              \
            int cs  = ch ^ (row & 3);                                                  \
            GLL16(wsrc + (size_t)row * EMBED + cs * 8, wb + c * 16);                   \
        }                                                                              \
    } while(0)

    // prologue: tiles 0 and 1 in flight
    STAGE(0, 0);
    STAGE(1, 1);

    for (int kt = 0; kt < NK; ++kt){
        const int bc = kt % 3;
        if (kt + 2 < NK){
            STAGE(kt + 2, (kt + 2) % 3);
            asm volatile("s_waitcnt vmcnt(10)" ::: "memory");   // tile kt done; kt+1,kt+2 in flight
        } else if (kt + 2 == NK){
            asm volatile("s_waitcnt vmcnt(5)" ::: "memory");    // tile kt done; kt+1 in flight
        } else {
            asm volatile("s_waitcnt vmcnt(0)" ::: "memory");
        }
        __builtin_amdgcn_s_barrier();

        char* xs_c = smem + bc * 8192;
        char* wl_c = smem + 24576 + bc * 12288;
        bf16x8 af[4], bfj[3];
        #pragma unroll
        for (int i = 0; i < 4; i++){
            int row = i * 16 + l15;
            int swz = row & 7;
            int c0  = lhi * 2;
            f32x4 lo = *(const f32x4*)(xs_c + row * 128 + ((c0    ) ^ swz) * 16);
            f32x4 hi = *(const f32x4*)(xs_c + row * 128 + ((c0 + 1) ^ swz) * 16);
            bf16x8 a;
            a[0] = (__bf16)lo[0]; a[1] = (__bf16)lo[1]; a[2] = (__bf16)lo[2]; a[3] = (__bf16)lo[3];
            a[4] = (__bf16)hi[0]; a[5] = (__bf16)hi[1]; a[6] = (__bf16)hi[2]; a[7] = (__bf16)hi[3];
            af[i] = a;
        }
        #pragma unroll
        for (int j = 0; j < 3; j++){
            int row = wid * 48 + j * 16 + l15;
            bfj[j] = *(const bf16x8*)(wl_c + row * 64 + ((lhi ^ (row & 3)) * 16));
        }
        #pragma unroll
        for (int i = 0; i < 4; i++)
            #pragma unroll
            for (int j = 0; j < 3; j++)
                acc[i][j] = MFMA16(af[i], bfj[j], acc[i][j]);

        __builtin_amdgcn_s_barrier();   // readers done before buffer bc is re-staged
    }
    #undef STAGE

    // ---- epilogue (r13-verified) ----
    float bval[3];
    #pragma unroll
    for (int j = 0; j < 3; j++){
        int c = half * 192 + wid * 48 + j * 16 + l15;
        bval[j] = (c < 128) ? bq[c] : ((c < 256) ? bk[c - 128] : bv[c - 256]);
    }
    #pragma unroll
    for (int j = 0; j < 3; j++){
        int cb = half * 192 + wid * 48 + j * 16;
        if (cb < 256){
            ushort* dst = (cb < 128) ? Qb : Kb;
            int cl = (cb < 128) ? (cb + l15) : (cb - 128 + l15);
            #pragma unroll
            for (int i = 0; i < 4; i++)
                #pragma unroll
                for (int r = 0; r < 4; r++)
                    dst[(size_t)(mtile*64 + i*16 + lhi*4 + r) * HEAD + cl] = f2bf(acc[i][j][r] + bval[j]);
        }
    }
    if (half == 1){
        __syncthreads();
        #pragma unroll
        for (int j = 0; j < 3; j++){
            int cb = 192 + wid * 48 + j * 16;
            if (cb >= 256){
                int vc = cb - 256 + l15;
                #pragma unroll
                for (int i = 0; i < 4; i++)
                    #pragma unroll
                    for (int r = 0; r < 4; r++)
                        ts[(i*16 + lhi*4 + r) * 132 + vc] = acc[i][j][r] + bval[j];
            }
        }
        __syncthreads();
        int n  = tid >> 1;
        int mc = (tid & 1) * 32;
        int bb = mtile >> 5;
        int trow = (mtile & 31) * 64 + mc;
        __attribute__((aligned(16))) ushort tmp[32];
        #pragma unroll
        for (int ii = 0; ii < 32; ii++) tmp[ii] = f2bf(ts[(mc + ii) * 132 + n]);
        ushort* dst = Vt + ((size_t)(bb * HEAD + n)) * SEQ + trow;
        #pragma unroll
        for (int q = 0; q < 4; q++)
            *(short8*)(dst + q * 8) = *(const short8*)(tmp + q * 8);
    }
}

// ---------------- Flash attention, causal, kv-split x2, async-staged ----------------
__global__ __launch_bounds__(256) void attn(const ushort* __restrict__ Qb,
                                            const ushort* __restrict__ Kb,
                                            const ushort* __restrict__ Vt,
                                            float* __restrict__ po,
                                            float* __restrict__ pm,
                                            float* __restrict__ pl){
    __shared__ char smem[40960];
    char* Ks = smem;
    char* Vs = smem + 16384;
    char* Ps = smem + 32768;

    const int slot = blockIdx.x;
    const int b    = blockIdx.y;
    const int qi   = slot >> 1;
    const int qt   = (b < 4) ? qi : (31 - qi);
    const int half = slot & 1;
    const int NT   = qt + 1;
    const int tmid = (NT + 1) >> 1;
    const int t0   = half ? tmid : 0;
    const int t1   = half ? NT : tmid;

    const int qb    = qt * 64;
    const int tid   = threadIdx.x;
    const int lane  = tid & 63, wid = tid >> 6;
    const int l15   = lane & 15, lhi = lane >> 4;
    const float scale = 0.08838834764831845f;

    bf16x8 qf[4];
    {
        const ushort* qp = Qb + ((size_t)(b * SEQ + qb + wid * 16 + l15)) * HEAD;
        #pragma unroll
        for (int kc = 0; kc < 4; kc++)
            qf[kc] = *(const bf16x8*)(qp + kc * 32 + lhi * 8);
    }

    f32x4 o[8];
    #pragma unroll
    for (int d = 0; d < 8; d++) o[d] = (f32x4){0.f,0.f,0.f,0.f};
    float mr[4] = {-1e30f,-1e30f,-1e30f,-1e30f};
    float lr[4] = {0.f,0.f,0.f,0.f};

    char* Pw = Ps + wid * 2048;

    const int krow = tid >> 4, kch = tid & 15;
    const int vd   = tid >> 3, vch = tid & 7;

    short8 kr[4], vr[4];
    {
        const int kvb = t0 * 64;
        #pragma unroll
        for (int j = 0; j < 4; j++)
            kr[j] = *(const short8*)(Kb + ((size_t)(b * SEQ + kvb + krow + 16*j)) * HEAD + kch * 8);
        #pragma unroll
        for (int j = 0; j < 4; j++)
            vr[j] = *(const short8*)(Vt + ((size_t)(b * HEAD + vd + 32*j)) * SEQ + kvb + vch * 8);
    }

    for (int t = t0; t < t1; ++t){
        __syncthreads();
        #pragma unroll
        for (int j = 0; j < 4; j++){
            int row = krow + 16*j;
            *(short8*)(Ks + row * 256 + ((kch ^ (row & 15)) * 16)) = kr[j];
        }
        #pragma unroll
        for (int j = 0; j < 4; j++){
            int d = vd + 32*j;
            *(short8*)(Vs + d * 128 + ((vch ^ (d & 7)) * 16)) = vr[j];
        }
        if (t + 1 < t1){
            const int kvb2 = (t + 1) * 64;
            #pragma unroll
            for (int j = 0; j < 4; j++)
                kr[j] = *(const short8*)(Kb + ((size_t)(b * SEQ + kvb2 + krow + 16*j)) * HEAD + kch * 8);
            #pragma unroll
            for (int j = 0; j < 4; j++)
                vr[j] = *(const short8*)(Vt + ((size_t)(b * HEAD + vd + 32*j)) * SEQ + kvb2 + vch * 8);
        }
        asm volatile("s_waitcnt lgkmcnt(0)" ::: "memory");
        __builtin_amdgcn_s_barrier();
        __builtin_amdgcn_sched_barrier(0);

        const int kvb = t * 64;
        f32x4 s[4];
        #pragma unroll
        for (int ns = 0; ns < 4; ns++){
            s[ns] = (f32x4){0.f,0.f,0.f,0.f};
            int row = ns * 16 + l15;
            #pragma unroll
            for (int kc = 0; kc < 4; kc++){
                int ch = (kc * 4 + lhi) ^ (row & 15);
                bf16x8 bfr = *(const bf16x8*)(Ks + row * 256 + ch * 16);
                s[ns] = MFMA16(qf[kc], bfr, s[ns]);
            }
        }

        float mx[4];
        #pragma unroll
        for (int r = 0; r < 4; r++){
            #pragma unroll
            for (int ns = 0; ns < 4; ns++){
                float v = s[ns][r] * scale;
                if (t == qt){
                    int kvg = kvb + ns * 16 + l15;
                    int qg  = qb + wid * 16 + lhi * 4 + r;
                    if (kvg > qg) v = -1e30f;
                }
                s[ns][r] = v;
            }
            float m0 = fmaxf(fmaxf(s[0][r], s[1][r]), fmaxf(s[2][r], s[3][r]));
            m0 = fmaxf(m0, __shfl_xor(m0, 1));
            m0 = fmaxf(m0, __shfl_xor(m0, 2));
            m0 = fmaxf(m0, __shfl_xor(m0, 4));
            m0 = fmaxf(m0, __shfl_xor(m0, 8));
            mx[r] = m0;
        }
        float alpha[4];
        #pragma unroll
        for (int r = 0; r < 4; r++){
            float mn = fmaxf(mr[r], mx[r]);
            alpha[r] = __expf(mr[r] - mn);
            mr[r] = mn;
            float sum = 0.f;
            #pragma unroll
            for (int ns = 0; ns < 4; ns++){
                float p = __expf(s[ns][r] - mn);
                s[ns][r] = p;
                sum += p;
            }
            sum += __shfl_xor(sum, 1);
            sum += __shfl_xor(sum, 2);
            sum += __shfl_xor(sum, 4);
            sum += __shfl_xor(sum, 8);
            lr[r] = lr[r] * alpha[r] + sum;
        }
        #pragma unroll
        for (int d = 0; d < 8; d++)
            #pragma unroll
            for (int r = 0; r < 4; r++) o[d][r] *= alpha[r];

        #pragma unroll
        for (int ns = 0; ns < 4; ns++)
            #pragma unroll
            for (int r = 0; r < 4; r++){
                int row = lhi * 4 + r;
                int byteoff = row * 128 + (((ns * 16 + l15) * 2) ^ ((row & 7) << 4));
                *(ushort*)(Pw + byteoff) = f2bf(s[ns][r]);
            }
        asm volatile("s_waitcnt lgkmcnt(0)" ::: "memory");
        __builtin_amdgcn_sched_barrier(0);

        #pragma unroll
        for (int kc = 0; kc < 2; kc++){
            int abyte = l15 * 128 + ((kc * 64 + lhi * 16) ^ ((l15 & 7) << 4));
            bf16x8 af = *(const bf16x8*)(Pw + abyte);
            #pragma unroll
            for (int ds = 0; ds < 8; ds++){
                int drow = ds * 16 + l15;
                int bbyte = drow * 128 + ((kc * 64 + lhi * 16) ^ ((drow & 7) << 4));
                bf16x8 bfr = *(const bf16x8*)(Vs + bbyte);
                o[ds] = MFMA16(af, bfr, o[ds]);
            }
        }
    }

    float* pob = po + ((size_t)half * 16384 + (size_t)b * SEQ) * HEAD;
    #pragma unroll
    for (int r = 0; r < 4; r++){
        int q = qb + wid * 16 + lhi * 4 + r;
        #pragma unroll
        for (int ds = 0; ds < 8; ds++)
            pob[(size_t)q * HEAD + ds * 16 + l15] = o[ds][r];
        if (l15 == 0){
            pm[half * 16384 + b * SEQ + q] = mr[r];
            pl[half * 16384 + b * SEQ + q] = lr[r];
        }
    }
}

// ---------------- merge two kv-halves ----------------
__global__ __launch_bounds__(256) void merge(const float* __restrict__ po,
                                             const float* __restrict__ pm,
                                             const float* __restrict__ pl,
                                             float* __restrict__ out){
    int g = blockIdx.x * 256 + threadIdx.x;
    int row = g >> 2;
    int dq  = (g & 3) * 32;
    float m0 = pm[row], m1 = pm[16384 + row];
    float l0 = pl[row], l1 = pl[16384 + row];
    float M  = fmaxf(m0, m1);
    float w0 = __expf(m0 - M), w1 = __expf(m1 - M);
    float inv = 1.0f / (w0 * l0 + w1 * l1);
    const float4* p0 = (const float4*)(po + (size_t)row * HEAD + dq);
    const float4* p1 = (const float4*)(po + (size_t)(16384 + row) * HEAD + dq);
    float4* op = (float4*)(out + (size_t)row * HEAD + dq);
    #pragma unroll
    for (int i = 0; i < 8; i++){
        float4 a = p0[i], c = p1[i];
        float4 r;
        r.x = (w0*a.x + w1*c.x) * inv;
        r.y = (w0*a.y + w1*c.y) * inv;
        r.z = (w0*a.z + w1*c.z) * inv;
        r.w = (w0*a.w + w1*c.w) * inv;
        op[i] = r;
    }
}

extern "C" void kernel_launch(void* const* d_in, const int* in_sizes, int n_in,
                              void* d_out, int out_size, void* d_ws, size_t ws_size,
                              hipStream_t stream){
    const float* x  = (const float*)d_in[0];
    const float* Wq = (const float*)d_in[1];
    const float* bq = (const float*)d_in[2];
    const float* Wk = (const float*)d_in[3];
    const float* bk = (const float*)d_in[4];
    const float* Wv = (const float*)d_in[5];
    const float* bv = (const float*)d_in[6];
    float* out = (float*)d_out;

    char* ws = (char*)d_ws;
    ushort* Qb = (ushort*)ws;
    ushort* Kb = (ushort*)(ws + (size_t)4  * 1024 * 1024);
    ushort* Vt = (ushort*)(ws + (size_t)8  * 1024 * 1024);
    ushort* Wt = (ushort*)(ws + (size_t)12 * 1024 * 1024);
    float*  po = (float*) (ws + (size_t)14 * 1024 * 1024);
    float*  pm = (float*) (ws + (size_t)31 * 1024 * 1024);
    float*  pl = (float*) (ws + (size_t)31 * 1024 * 1024 + 262144);

    prep_wt <<<dim3(32, 3), 256, 0, stream>>>(Wq, Wk, Wv, Wt);
    qkv_gemm<<<dim3(2, 256), 256, 0, stream>>>(x, Wt, bq, bk, bv, Qb, Kb, Vt);
    attn    <<<dim3(64, 8), 256, 0, stream>>>(Qb, Kb, Vt, po, pm, pl);
    merge   <<<256, 256, 0, stream>>>(po, pm, pl, out);
}

// Round 17
// 100.418 us; speedup vs baseline: 3.2961x; 1.2236x over previous
//
#include <hip/hip_runtime.h>

#define EMBED 2048
#define HEAD 128
#define BATCH 8
#define SEQ 2048

typedef __attribute__((ext_vector_type(4))) float f32x4;
typedef __attribute__((ext_vector_type(8))) __bf16 bf16x8;
typedef __attribute__((ext_vector_type(8))) short short8;

static __device__ __forceinline__ ushort f2bf(float x){
    unsigned u = __float_as_uint(x);
    u += 0x7fffu + ((u >> 16) & 1u);
    return (ushort)(u >> 16);
}

#define MFMA16(a,b,c) __builtin_amdgcn_mfma_f32_16x16x32_bf16((a),(b),(c),0,0,0)

#define GLL16(g, l) __builtin_amdgcn_global_load_lds( \
    (const __attribute__((address_space(1))) void*)(g), \
    (__attribute__((address_space(3))) void*)(l), 16, 0, 0)

// ---------------- prep: W [2048][128] f32 -> W^T [3*128][2048] bf16 (LDS transpose) ----------------
__global__ __launch_bounds__(256) void prep_wt(const float* __restrict__ Wq,
                                               const float* __restrict__ Wk,
                                               const float* __restrict__ Wv,
                                               ushort* __restrict__ wt){
    __shared__ float ld[64][129];
    const int w  = blockIdx.y;
    const int k0 = blockIdx.x * 64;
    const int tid = threadIdx.x;
    const float* W = (w == 0) ? Wq : ((w == 1) ? Wk : Wv);
    #pragma unroll
    for (int ii = 0; ii < 32; ii++){
        int idx = tid + 256 * ii;
        int row = idx >> 7, col = idx & 127;
        ld[row][col] = W[(size_t)(k0 + row) * HEAD + col];
    }
    __syncthreads();
    int n  = tid >> 1;
    int kh = (tid & 1) * 32;
    __attribute__((aligned(16))) ushort tmp[32];
    #pragma unroll
    for (int ii = 0; ii < 32; ii++) tmp[ii] = f2bf(ld[kh + ii][n]);
    ushort* dst = wt + (size_t)(w * HEAD + n) * EMBED + k0 + kh;
    #pragma unroll
    for (int q = 0; q < 4; q++)
        *(short8*)(dst + q * 8) = *(const short8*)(tmp + q * 8);
}

// ---------------- Fused QKV GEMM: [16384 x 2048] x [2048 x 384], x read ONCE (r7 verbatim) ----------------
// BM=64, BN=384, BK=64, 512 thr (8 waves, 2m x 4n; wave tile 32x96). Grid 256 = 1 block/CU.
// x: reg-staged f32->bf16 (8 f32/thread/iter); W: GLL direct-to-LDS, full double-buffer.
__global__ __launch_bounds__(512) void qkv_gemm(const float* __restrict__ x,
                                                const ushort* __restrict__ wt,
                                                const float* __restrict__ bq,
                                                const float* __restrict__ bk,
                                                const float* __restrict__ bv,
                                                ushort* __restrict__ Qb,
                                                ushort* __restrict__ Kb,
                                                ushort* __restrict__ Vt){
    __shared__ char smem[116736];
    // xsb(buf) = smem + buf*9216             [64][144B] padded bf16
    // wlb(buf) = smem + 18432 + buf*49152    [384][128B] linear, chunk-swizzled
    float* ts = (float*)smem;                  // epilogue V transpose [64][132] f32

    const int mtile = blockIdx.x;
    const int tid   = threadIdx.x;
    const int lane  = tid & 63;
    const int wid   = tid >> 6;                // 0..7
    const int l15   = lane & 15, lhi = lane >> 4;
    const int wm    = wid >> 2,  wn  = wid & 3;
    const int xrow0 = mtile * 64;

    const int srow = tid >> 3;      // 0..63 (x stage row)
    const int ssub = tid & 7;       // 8-f32 chunk within row

    const int grow = lane >> 3;     // gll: row within 8-row group
    const int gch  = lane & 7;      // gll: 16B chunk

    f32x4 acc[2][6];
    #pragma unroll
    for (int i = 0; i < 2; i++)
        #pragma unroll
        for (int j = 0; j < 6; j++) acc[i][j] = (f32x4){0.f,0.f,0.f,0.f};

    float4 xr0, xr1;
    const int NK = EMBED / 64;

    // ---- prologue: stage kt=0 ----
    {
        const float* xp = x + (size_t)(xrow0 + srow) * EMBED;
        xr0 = *(const float4*)(xp + ssub * 8);
        xr1 = *(const float4*)(xp + ssub * 8 + 4);
        #pragma unroll
        for (int g = 0; g < 6; g++){
            int r0  = wid * 48 + g * 8;
            int row = r0 + grow;
            GLL16(wt + (size_t)row * EMBED + ((gch ^ grow) * 8), smem + 18432 + r0 * 128);
        }
        __attribute__((aligned(16))) ushort t8[8];
        t8[0]=f2bf(xr0.x); t8[1]=f2bf(xr0.y); t8[2]=f2bf(xr0.z); t8[3]=f2bf(xr0.w);
        t8[4]=f2bf(xr1.x); t8[5]=f2bf(xr1.y); t8[6]=f2bf(xr1.z); t8[7]=f2bf(xr1.w);
        *(short8*)(smem + srow * 144 + ssub * 16) = *(const short8*)t8;
    }
    __syncthreads();

    int cur = 0;
    for (int kt = 0; kt < NK; ++kt){
        char* xsb_c = smem + cur * 9216;
        char* wlb_c = smem + 18432 + cur * 49152;
        char* xsb_n = smem + (cur ^ 1) * 9216;
        char* wlb_n = smem + 18432 + (cur ^ 1) * 49152;
        // issue next-tile loads early (hidden under compute; barrier drains at end)
        if (kt < NK - 1){
            const float* xp = x + (size_t)(xrow0 + srow) * EMBED + (kt + 1) * 64;
            xr0 = *(const float4*)(xp + ssub * 8);
            xr1 = *(const float4*)(xp + ssub * 8 + 4);
            const ushort* wsrc = wt + (kt + 1) * 64;
            #pragma unroll
            for (int g = 0; g < 6; g++){
                int r0  = wid * 48 + g * 8;
                int row = r0 + grow;
                GLL16(wsrc + (size_t)row * EMBED + ((gch ^ grow) * 8), wlb_n + r0 * 128);
            }
        }
        // compute from current buffer  (A rows: wm*32 + i*16 + l15 — r7 verbatim)
        #pragma unroll
        for (int kc = 0; kc < 2; kc++){
            bf16x8 af[2], bfj[6];
            #pragma unroll
            for (int i = 0; i < 2; i++)
                af[i] = *(const bf16x8*)(xsb_c + (wm*32 + i*16 + l15) * 144 + kc*64 + lhi*16);
            #pragma unroll
            for (int j = 0; j < 6; j++){
                int row = wn*96 + j*16 + l15;
                bfj[j] = *(const bf16x8*)(wlb_c + row * 128 + (((kc*4 + lhi) ^ (l15 & 7)) * 16));
            }
            #pragma unroll
            for (int i = 0; i < 2; i++)
                #pragma unroll
                for (int j = 0; j < 6; j++)
                    acc[i][j] = MFMA16(af[i], bfj[j], acc[i][j]);
        }
        // write staged x into next buffer
        if (kt < NK - 1){
            __attribute__((aligned(16))) ushort t8[8];
            t8[0]=f2bf(xr0.x); t8[1]=f2bf(xr0.y); t8[2]=f2bf(xr0.z); t8[3]=f2bf(xr0.w);
            t8[4]=f2bf(xr1.x); t8[5]=f2bf(xr1.y); t8[6]=f2bf(xr1.z); t8[7]=f2bf(xr1.w);
            *(short8*)(xsb_n + srow * 144 + ssub * 16) = *(const short8*)t8;
        }
        __syncthreads();
        cur ^= 1;
    }

    // ---- epilogue (r7 verbatim) ----
    float bval[6];
    #pragma unroll
    for (int j = 0; j < 6; j++){
        int c = wn*96 + j*16 + l15;
        bval[j] = (c < 128) ? bq[c] : ((c < 256) ? bk[c - 128] : bv[c - 256]);
    }
    // Q/K direct stores; V -> ts (f32) for transpose
    #pragma unroll
    for (int j = 0; j < 6; j++){
        int cb = wn*96 + j*16;          // 16-aligned; each j-block wholly in Q, K, or V
        if (cb < 256){
            ushort* dst = (cb < 128) ? Qb : Kb;
            int cl = (cb & 127) + l15;
            #pragma unroll
            for (int i = 0; i < 2; i++)
                #pragma unroll
                for (int r = 0; r < 4; r++){
                    int m = mtile*64 + wm*32 + i*16 + lhi*4 + r;
                    dst[(size_t)m * HEAD + cl] = f2bf(acc[i][j][r] + bval[j]);
                }
        } else {
            int vc = cb - 256 + l15;
            #pragma unroll
            for (int i = 0; i < 2; i++)
                #pragma unroll
                for (int r = 0; r < 4; r++){
                    int ml = wm*32 + i*16 + lhi*4 + r;
                    ts[ml * 132 + vc] = acc[i][j][r] + bval[j];
                }
        }
    }
    __syncthreads();
    // transpose out: V [64 rows][128 cols] -> Vt [8][128][2048]
    {
        int n  = tid >> 2;              // 0..127 V col
        int mc = (tid & 3) * 16;        // row group
        int bb = mtile >> 5;
        int trow = (mtile & 31) * 64 + mc;
        __attribute__((aligned(16))) ushort tmp[16];
        #pragma unroll
        for (int ii = 0; ii < 16; ii++) tmp[ii] = f2bf(ts[(mc + ii) * 132 + n]);
        ushort* dst = Vt + ((size_t)(bb * HEAD + n)) * SEQ + trow;
        *(short8*)(dst)     = *(const short8*)(tmp);
        *(short8*)(dst + 8) = *(const short8*)(tmp + 8);
    }
}

// ---------------- Flash attention, causal, kv-split x2, async-staged (+T5 setprio) ----------------
__global__ __launch_bounds__(256) void attn(const ushort* __restrict__ Qb,
                                            const ushort* __restrict__ Kb,
                                            const ushort* __restrict__ Vt,
                                            float* __restrict__ po,
                                            float* __restrict__ pm,
                                            float* __restrict__ pl){
    __shared__ char smem[40960];
    char* Ks = smem;            // [64 kv][256 B] chunk-swizzled (^row&15)
    char* Vs = smem + 16384;    // [128 d][128 B] chunk-swizzled (^d&7)
    char* Ps = smem + 32768;    // 4 waves x [16 q][128 B] chunk-swizzled (^q&7)

    const int slot = blockIdx.x;
    const int b    = blockIdx.y;
    const int qi   = slot >> 1;
    const int qt   = (b < 4) ? qi : (31 - qi);     // anti-correlated pairing
    const int half = slot & 1;
    const int NT   = qt + 1;
    const int tmid = (NT + 1) >> 1;
    const int t0   = half ? tmid : 0;
    const int t1   = half ? NT : tmid;

    const int qb    = qt * 64;
    const int tid   = threadIdx.x;
    const int lane  = tid & 63, wid = tid >> 6;
    const int l15   = lane & 15, lhi = lane >> 4;
    const float scale = 0.08838834764831845f;   // 1/sqrt(128)

    bf16x8 qf[4];
    {
        const ushort* qp = Qb + ((size_t)(b * SEQ + qb + wid * 16 + l15)) * HEAD;
        #pragma unroll
        for (int kc = 0; kc < 4; kc++)
            qf[kc] = *(const bf16x8*)(qp + kc * 32 + lhi * 8);
    }

    f32x4 o[8];
    #pragma unroll
    for (int d = 0; d < 8; d++) o[d] = (f32x4){0.f,0.f,0.f,0.f};
    float mr[4] = {-1e30f,-1e30f,-1e30f,-1e30f};
    float lr[4] = {0.f,0.f,0.f,0.f};

    char* Pw = Ps + wid * 2048;

    const int krow = tid >> 4, kch = tid & 15;   // K stage coords
    const int vd   = tid >> 3, vch = tid & 7;    // V stage coords

    short8 kr[4], vr[4];
    {
        const int kvb = t0 * 64;
        #pragma unroll
        for (int j = 0; j < 4; j++)
            kr[j] = *(const short8*)(Kb + ((size_t)(b * SEQ + kvb + krow + 16*j)) * HEAD + kch * 8);
        #pragma unroll
        for (int j = 0; j < 4; j++)
            vr[j] = *(const short8*)(Vt + ((size_t)(b * HEAD + vd + 32*j)) * SEQ + kvb + vch * 8);
    }

    for (int t = t0; t < t1; ++t){
        __syncthreads();
        #pragma unroll
        for (int j = 0; j < 4; j++){
            int row = krow + 16*j;
            *(short8*)(Ks + row * 256 + ((kch ^ (row & 15)) * 16)) = kr[j];
        }
        #pragma unroll
        for (int j = 0; j < 4; j++){
            int d = vd + 32*j;
            *(short8*)(Vs + d * 128 + ((vch ^ (d & 7)) * 16)) = vr[j];
        }
        if (t + 1 < t1){
            const int kvb2 = (t + 1) * 64;
            #pragma unroll
            for (int j = 0; j < 4; j++)
                kr[j] = *(const short8*)(Kb + ((size_t)(b * SEQ + kvb2 + krow + 16*j)) * HEAD + kch * 8);
            #pragma unroll
            for (int j = 0; j < 4; j++)
                vr[j] = *(const short8*)(Vt + ((size_t)(b * HEAD + vd + 32*j)) * SEQ + kvb2 + vch * 8);
        }
        asm volatile("s_waitcnt lgkmcnt(0)" ::: "memory");
        __builtin_amdgcn_s_barrier();
        __builtin_amdgcn_sched_barrier(0);

        const int kvb = t * 64;
        f32x4 s[4];
        __builtin_amdgcn_s_setprio(1);
        #pragma unroll
        for (int ns = 0; ns < 4; ns++){
            s[ns] = (f32x4){0.f,0.f,0.f,0.f};
            int row = ns * 16 + l15;
            #pragma unroll
            for (int kc = 0; kc < 4; kc++){
                int ch = (kc * 4 + lhi) ^ (row & 15);
                bf16x8 bfr = *(const bf16x8*)(Ks + row * 256 + ch * 16);
                s[ns] = MFMA16(qf[kc], bfr, s[ns]);
            }
        }
        __builtin_amdgcn_s_setprio(0);

        float mx[4];
        #pragma unroll
        for (int r = 0; r < 4; r++){
            #pragma unroll
            for (int ns = 0; ns < 4; ns++){
                float v = s[ns][r] * scale;
                if (t == qt){
                    int kvg = kvb + ns * 16 + l15;
                    int qg  = qb + wid * 16 + lhi * 4 + r;
                    if (kvg > qg) v = -1e30f;
                }
                s[ns][r] = v;
            }
            float m0 = fmaxf(fmaxf(s[0][r], s[1][r]), fmaxf(s[2][r], s[3][r]));
            m0 = fmaxf(m0, __shfl_xor(m0, 1));
            m0 = fmaxf(m0, __shfl_xor(m0, 2));
            m0 = fmaxf(m0, __shfl_xor(m0, 4));
            m0 = fmaxf(m0, __shfl_xor(m0, 8));
            mx[r] = m0;
        }
        float alpha[4];
        #pragma unroll
        for (int r = 0; r < 4; r++){
            float mn = fmaxf(mr[r], mx[r]);
            alpha[r] = __expf(mr[r] - mn);
            mr[r] = mn;
            float sum = 0.f;
            #pragma unroll
            for (int ns = 0; ns < 4; ns++){
                float p = __expf(s[ns][r] - mn);
                s[ns][r] = p;
                sum += p;
            }
            sum += __shfl_xor(sum, 1);
            sum += __shfl_xor(sum, 2);
            sum += __shfl_xor(sum, 4);
            sum += __shfl_xor(sum, 8);
            lr[r] = lr[r] * alpha[r] + sum;
        }
        #pragma unroll
        for (int d = 0; d < 8; d++)
            #pragma unroll
            for (int r = 0; r < 4; r++) o[d][r] *= alpha[r];

        #pragma unroll
        for (int ns = 0; ns < 4; ns++)
            #pragma unroll
            for (int r = 0; r < 4; r++){
                int row = lhi * 4 + r;
                int byteoff = row * 128 + (((ns * 16 + l15) * 2) ^ ((row & 7) << 4));
                *(ushort*)(Pw + byteoff) = f2bf(s[ns][r]);
            }
        asm volatile("s_waitcnt lgkmcnt(0)" ::: "memory");
        __builtin_amdgcn_sched_barrier(0);

        __builtin_amdgcn_s_setprio(1);
        #pragma unroll
        for (int kc = 0; kc < 2; kc++){
            int abyte = l15 * 128 + ((kc * 64 + lhi * 16) ^ ((l15 & 7) << 4));
            bf16x8 af = *(const bf16x8*)(Pw + abyte);
            #pragma unroll
            for (int ds = 0; ds < 8; ds++){
                int drow = ds * 16 + l15;
                int bbyte = drow * 128 + ((kc * 64 + lhi * 16) ^ ((drow & 7) << 4));
                bf16x8 bfr = *(const bf16x8*)(Vs + bbyte);
                o[ds] = MFMA16(af, bfr, o[ds]);
            }
        }
        __builtin_amdgcn_s_setprio(0);
    }

    float* pob = po + ((size_t)half * 16384 + (size_t)b * SEQ) * HEAD;
    #pragma unroll
    for (int r = 0; r < 4; r++){
        int q = qb + wid * 16 + lhi * 4 + r;
        #pragma unroll
        for (int ds = 0; ds < 8; ds++)
            pob[(size_t)q * HEAD + ds * 16 + l15] = o[ds][r];
        if (l15 == 0){
            pm[half * 16384 + b * SEQ + q] = mr[r];
            pl[half * 16384 + b * SEQ + q] = lr[r];
        }
    }
}

// ---------------- merge two kv-halves ----------------
__global__ __launch_bounds__(256) void merge(const float* __restrict__ po,
                                             const float* __restrict__ pm,
                                             const float* __restrict__ pl,
                                             float* __restrict__ out){
    int g = blockIdx.x * 256 + threadIdx.x;
    int row = g >> 2;
    int dq  = (g & 3) * 32;
    float m0 = pm[row], m1 = pm[16384 + row];
    float l0 = pl[row], l1 = pl[16384 + row];
    float M  = fmaxf(m0, m1);
    float w0 = __expf(m0 - M), w1 = __expf(m1 - M);
    float inv = 1.0f / (w0 * l0 + w1 * l1);
    const float4* p0 = (const float4*)(po + (size_t)row * HEAD + dq);
    const float4* p1 = (const float4*)(po + (size_t)(16384 + row) * HEAD + dq);
    float4* op = (float4*)(out + (size_t)row * HEAD + dq);
    #pragma unroll
    for (int i = 0; i < 8; i++){
        float4 a = p0[i], c = p1[i];
        float4 r;
        r.x = (w0*a.x + w1*c.x) * inv;
        r.y = (w0*a.y + w1*c.y) * inv;
        r.z = (w0*a.z + w1*c.z) * inv;
        r.w = (w0*a.w + w1*c.w) * inv;
        op[i] = r;
    }
}

extern "C" void kernel_launch(void* const* d_in, const int* in_sizes, int n_in,
                              void* d_out, int out_size, void* d_ws, size_t ws_size,
                              hipStream_t stream){
    const float* x  = (const float*)d_in[0];
    const float* Wq = (const float*)d_in[1];
    const float* bq = (const float*)d_in[2];
    const float* Wk = (const float*)d_in[3];
    const float* bk = (const float*)d_in[4];
    const float* Wv = (const float*)d_in[5];
    const float* bv = (const float*)d_in[6];
    float* out = (float*)d_out;

    char* ws = (char*)d_ws;
    ushort* Qb = (ushort*)ws;                                  // 4 MB   [16384][128]
    ushort* Kb = (ushort*)(ws + (size_t)4  * 1024 * 1024);     // 4 MB   [16384][128]
    ushort* Vt = (ushort*)(ws + (size_t)8  * 1024 * 1024);     // 4 MB   [8][128][2048]
    ushort* Wt = (ushort*)(ws + (size_t)12 * 1024 * 1024);     // 1.57MB [384][2048]
    float*  po = (float*) (ws + (size_t)14 * 1024 * 1024);     // 16.8MB [2][16384][128]
    float*  pm = (float*) (ws + (size_t)31 * 1024 * 1024);     // 131KB  [2][16384]
    float*  pl = (float*) (ws + (size_t)31 * 1024 * 1024 + 262144);

    prep_wt <<<dim3(32, 3), 256, 0, stream>>>(Wq, Wk, Wv, Wt);
    qkv_gemm<<<dim3(256), 512, 0, stream>>>(x, Wt, bq, bk, bv, Qb, Kb, Vt);
    attn    <<<dim3(64, 8), 256, 0, stream>>>(Qb, Kb, Vt, po, pm, pl);
    merge   <<<256, 256, 0, stream>>>(po, pm, pl, out);
}